// Round 4
// baseline (105.666 us; speedup 1.0000x reference)
//
#include <hip/hip_runtime.h>
#include <math.h>

#define BATCH 4
#define NN    12288
#define CIN   3
#define NC    4096
#define NG    12
#define NB    256          // a-buckets per group
#define NCOPY 4            // privatized LDS histogram copies (4 waves share one)

#define CPOFF 0            // coupling buffer in ws: [BATCH*NN*4] floats

// ---------- kernel 1: per (group,dim): bucketed prefix sums -> coupling ----
// Exact pair math for cross-bucket pairs; same-bucket pairs with a_j > a_i
// use the lower-side formula (error <= ~2*delta per pair, ~4e-6 total).
__launch_bounds__(1024)
__global__ void k_bucket(const float* __restrict__ spikes,
                         const float* __restrict__ theta,
                         float* __restrict__ ws) {
    __shared__ float hist[NCOPY][8][NB];          // 32 KB
    __shared__ float redmn[16], redmx[16];
    __shared__ float uScale, uAmin, uInv;

    int bid = blockIdx.x;
    int g = bid >> 2, d = bid & 3;
    int b = g / CIN, c = g % CIN;
    int tid = threadIdx.x, lane = tid & 63, w = tid >> 6;
    int cpy = w >> 2;

    // zero histograms (NCOPY*8*NB = 8192 floats)
    float* hflat = &hist[0][0][0];
    #pragma unroll
    for (int q = 0; q < 8; ++q) hflat[tid + q * 1024] = 0.f;

    // load s and theta_d for this block's 4096 elements
    float s[4], th[4];
    #pragma unroll
    for (int q = 0; q < 4; ++q) {
        int k = tid + q * 1024;
        int v = b * NN + k * CIN + c;
        s[q]  = spikes[v];
        th[q] = theta[v * 4 + d];
    }
    float mn = fminf(fminf(s[0], s[1]), fminf(s[2], s[3]));
    float mx = fmaxf(fmaxf(s[0], s[1]), fmaxf(s[2], s[3]));
    #pragma unroll
    for (int off = 32; off; off >>= 1) {
        mn = fminf(mn, __shfl_down(mn, off));
        mx = fmaxf(mx, __shfl_down(mx, off));
    }
    if (lane == 0) { redmn[w] = mn; redmx[w] = mx; }
    __syncthreads();                 // covers hist zero too
    if (tid == 0) {
        float m0 = redmn[0], m1 = redmx[0];
        for (int i = 1; i < 16; ++i) { m0 = fminf(m0, redmn[i]); m1 = fmaxf(m1, redmx[i]); }
        float scale = 0.25f / fmaxf(m1 - m0, 1e-6f);
        uScale = scale;
        uAmin  = m0 * scale;
        uInv   = (float)NB / fmaxf((m1 - m0) * scale, 1e-30f);
    }
    __syncthreads();
    float scale = uScale, amin = uAmin, inv = uInv;

    // per-element channels -> bucket accumulate
    float a[4], sf[4], cf[4], sp[4], cq[4]; int bk[4];
    #pragma unroll
    for (int q = 0; q < 4; ++q) {
        a[q] = s[q] * scale;
        int bb = (int)((a[q] - amin) * inv);
        bk[q] = bb < 0 ? 0 : (bb > NB - 1 ? NB - 1 : bb);
        float sth, cth, sa, ca;
        sincosf(th[q], &sth, &cth);
        sincosf(a[q], &sa, &ca);
        sf[q] = fmaf(cth, sa,  sth * ca);     // sin(th + a)
        cf[q] = fmaf(-sth, sa, cth * ca);     // cos(th + a)
        sp[q] = fmaf(-cth, sa, sth * ca);     // sin(th - a)
        cq[q] = fmaf(sth, sa,  cth * ca);     // cos(th - a)
        atomicAdd(&hist[cpy][0][bk[q]], sf[q]);
        atomicAdd(&hist[cpy][1][bk[q]], cf[q]);
        atomicAdd(&hist[cpy][2][bk[q]], a[q] * sf[q]);
        atomicAdd(&hist[cpy][3][bk[q]], a[q] * cf[q]);
        atomicAdd(&hist[cpy][4][bk[q]], sp[q]);
        atomicAdd(&hist[cpy][5][bk[q]], cq[q]);
        atomicAdd(&hist[cpy][6][bk[q]], a[q] * sp[q]);
        atomicAdd(&hist[cpy][7][bk[q]], a[q] * cq[q]);
    }
    __syncthreads();

    // combine privatized copies into copy 0 (each slot owned by one thread)
    #pragma unroll
    for (int q = 0; q < 2; ++q) {
        int o = tid + q * 1024;               // 0..2047
        int ch = o >> 8, bb = o & (NB - 1);
        hist[0][ch][bb] = (hist[0][ch][bb] + hist[1][ch][bb]) +
                          (hist[2][ch][bb] + hist[3][ch][bb]);
    }
    __syncthreads();

    // inclusive prefix scan over buckets, one wave per channel
    if (tid < 512) {
        int ch = w;
        float x0 = hist[0][ch][lane * 4 + 0];
        float x1 = hist[0][ch][lane * 4 + 1];
        float x2 = hist[0][ch][lane * 4 + 2];
        float x3 = hist[0][ch][lane * 4 + 3];
        float i0 = x0, i1 = i0 + x1, i2 = i1 + x2, i3 = i2 + x3;
        float incl = i3;
        #pragma unroll
        for (int off = 1; off < 64; off <<= 1) {
            float o = __shfl_up(incl, off);
            if (lane >= off) incl += o;
        }
        float ebt = incl - i3;
        hist[0][ch][lane * 4 + 0] = ebt + i0;
        hist[0][ch][lane * 4 + 1] = ebt + i1;
        hist[0][ch][lane * 4 + 2] = ebt + i2;
        hist[0][ch][lane * 4 + 3] = ebt + i3;
    }
    __syncthreads();

    // per-element combine -> coupling
    float t4 = hist[0][4][NB - 1], t5 = hist[0][5][NB - 1];
    float t6 = hist[0][6][NB - 1], t7 = hist[0][7][NB - 1];
    const float kInv = 1.0f / (float)NC;
    #pragma unroll
    for (int q = 0; q < 4; ++q) {
        int bb = bk[q];
        float P0 = hist[0][0][bb], P1 = hist[0][1][bb];
        float P2 = hist[0][2][bb], P3 = hist[0][3][bb];
        float P4 = hist[0][4][bb], P5 = hist[0][5][bb];
        float P6 = hist[0][6][bb], P7 = hist[0][7][bb];
        float lowS = fmaf(0.25f - a[q], P0, P2);
        float lowC = fmaf(0.25f - a[q], P1, P3);
        float lower = cf[q] * lowS - sf[q] * lowC;
        float S4 = t4 - P4, S5 = t5 - P5, S6 = t6 - P6, S7 = t7 - P7;
        float upS = fmaf(0.25f + a[q], S4, -S6);
        float upC = fmaf(0.25f + a[q], S5, -S7);
        float upper = cq[q] * upS - sp[q] * upC;
        int k = tid + q * 1024;
        int v = b * NN + k * CIN + c;
        ws[CPOFF + v * 4 + d] = (lower + upper) * kInv;
    }
}

// ---------- kernel 2: theta_next = gamma + coupling, normalize -------------
__global__ void k_norm(const float* __restrict__ gamma,
                       const float* __restrict__ ws,
                       float* __restrict__ out) {
    int u = blockIdx.x * 256 + threadIdx.x;    // < BATCH*NN
    float4 cp = ((const float4*)(ws + CPOFF))[u];
    float4 g4 = ((const float4*)gamma)[u];
    float tx = g4.x + cp.x, ty = g4.y + cp.y, tz = g4.z + cp.z, tw = g4.w + cp.w;
    float nrm = sqrtf(tx * tx + ty * ty + tz * tz + tw * tw);
    float inv = 1.0f / fmaxf(nrm, 1e-6f);
    ((float4*)out)[u] = make_float4(tx * inv, ty * inv, tz * inv, tw * inv);
}

extern "C" void kernel_launch(void* const* d_in, const int* in_sizes, int n_in,
                              void* d_out, int out_size, void* d_ws, size_t ws_size,
                              hipStream_t stream) {
    const float* theta  = (const float*)d_in[0];
    const float* gamma  = (const float*)d_in[1];
    const float* spikes = (const float*)d_in[2];
    float* out = (float*)d_out;
    float* ws  = (float*)d_ws;

    hipLaunchKernelGGL(k_bucket, dim3(NG * 4),        dim3(1024), 0, stream, spikes, theta, ws);
    hipLaunchKernelGGL(k_norm,   dim3(BATCH*NN/256),  dim3(256),  0, stream, gamma, ws, out);
}

// Round 5
// 82.986 us; speedup vs baseline: 1.2733x; 1.2733x over previous
//
#include <hip/hip_runtime.h>
#include <math.h>

#define BATCH 4
#define NN    12288
#define CIN   3
#define NC    4096
#define NG    12
#define NB    256
#define LH_STRIDE 9          // LDS bucket stride (coprime with 32 banks)

// ws layout (float offsets)
#define SC_OFF 0             // per group: scale, amin  [NG*2]
#define H_OFF  64            // HIST [NG][4][NB][8] = 98304 floats

// ---------- kernel 1: per-group min/max -> scale/amin; zero histogram ------
__launch_bounds__(256)
__global__ void k_stats(const float* __restrict__ spikes, float* __restrict__ ws) {
    int g = blockIdx.x, b = g / CIN, c = g % CIN;
    int tid = threadIdx.x, lane = tid & 63, w = tid >> 6;
    float mn = 1e30f, mx = -1e30f;
    #pragma unroll
    for (int q = 0; q < 16; ++q) {
        float s = spikes[b*NN + (tid + q*256)*CIN + c];
        mn = fminf(mn, s); mx = fmaxf(mx, s);
    }
    #pragma unroll
    for (int off = 32; off; off >>= 1) {
        mn = fminf(mn, __shfl_down(mn, off));
        mx = fmaxf(mx, __shfl_down(mx, off));
    }
    __shared__ float smn[4], smx[4];
    if (lane == 0) { smn[w] = mn; smx[w] = mx; }
    __syncthreads();
    if (tid == 0) {
        float m0 = fminf(fminf(smn[0], smn[1]), fminf(smn[2], smn[3]));
        float m1 = fmaxf(fmaxf(smx[0], smx[1]), fmaxf(smx[2], smx[3]));
        float scale = 0.25f / fmaxf(m1 - m0, 1e-6f);
        ws[SC_OFF + g*2]     = scale;
        ws[SC_OFF + g*2 + 1] = m0 * scale;
    }
    // zero this group's histogram slice: 8192 floats = 2048 float4
    float4* hz = (float4*)(ws + H_OFF) + g * 2048;
    #pragma unroll
    for (int q = 0; q < 8; ++q)
        hz[tid + q*256] = make_float4(0.f, 0.f, 0.f, 0.f);
}

// ---------- kernel 2: per (group-chunk): LDS hist -> global atomic merge ---
__launch_bounds__(256)
__global__ void k_hist(const float* __restrict__ spikes,
                       const float* __restrict__ theta,
                       float* __restrict__ ws) {
    __shared__ float lh[4 * NB * LH_STRIDE];   // 36 KB
    int blk = blockIdx.x, g = blk >> 4, chunk = blk & 15;
    int b = g / CIN, c = g % CIN;
    int tid = threadIdx.x;
    #pragma unroll
    for (int q = 0; q < 36; ++q) lh[tid + q*256] = 0.f;

    float scale = ws[SC_OFF + g*2], amin = ws[SC_OFF + g*2 + 1];
    int k = chunk*256 + tid;
    int v = b*NN + k*CIN + c;
    float s = spikes[v];
    float4 th = ((const float4*)theta)[v];
    float a = s * scale;
    int bb = (int)((a - amin) * (4.0f * NB));
    bb = bb < 0 ? 0 : (bb > NB - 1 ? NB - 1 : bb);
    float sa, ca; sincosf(a, &sa, &ca);
    float thv[4] = {th.x, th.y, th.z, th.w};
    __syncthreads();

    #pragma unroll
    for (int d = 0; d < 4; ++d) {
        float sth, cth; sincosf(thv[d], &sth, &cth);
        float sf = fmaf(cth, sa,  sth*ca);   // sin(th + a)
        float cf = fmaf(-sth, sa, cth*ca);   // cos(th + a)
        float sp = fmaf(-cth, sa, sth*ca);   // sin(th - a)
        float cq = fmaf(sth, sa,  cth*ca);   // cos(th - a)
        float* h = lh + (d*NB + bb) * LH_STRIDE;
        atomicAdd(h + 0, sf);     atomicAdd(h + 1, cf);
        atomicAdd(h + 2, a * sf); atomicAdd(h + 3, a * cf);
        atomicAdd(h + 4, sp);     atomicAdd(h + 5, cq);
        atomicAdd(h + 6, a * sp); atomicAdd(h + 7, a * cq);
    }
    __syncthreads();

    float* H = ws + H_OFF + g * 8192;
    #pragma unroll
    for (int q = 0; q < 32; ++q) {
        int o = tid + q*256;                 // (d*NB+bb)*8 + ch
        int db = o >> 3, ch = o & 7;
        float vv = lh[db * LH_STRIDE + ch];
        if (vv != 0.f) atomicAdd(&H[o], vv);
    }
}

// ---------- kernel 3: inclusive prefix over buckets per (g,d,ch) -----------
__launch_bounds__(512)
__global__ void k_scan(float* __restrict__ ws) {
    float* H = ws + H_OFF + blockIdx.x * 2048;   // one (g,d): [NB][8]
    int tid = threadIdx.x, lane = tid & 63, ch = tid >> 6;
    float x0 = H[(lane*4 + 0)*8 + ch];
    float x1 = H[(lane*4 + 1)*8 + ch];
    float x2 = H[(lane*4 + 2)*8 + ch];
    float x3 = H[(lane*4 + 3)*8 + ch];
    float i0 = x0, i1 = i0 + x1, i2 = i1 + x2, i3 = i2 + x3;
    float incl = i3;
    #pragma unroll
    for (int off = 1; off < 64; off <<= 1) {
        float o = __shfl_up(incl, off);
        if (lane >= off) incl += o;
    }
    float ebt = incl - i3;
    H[(lane*4 + 0)*8 + ch] = ebt + i0;
    H[(lane*4 + 1)*8 + ch] = ebt + i1;
    H[(lane*4 + 2)*8 + ch] = ebt + i2;
    H[(lane*4 + 3)*8 + ch] = ebt + i3;
}

// ---------- kernel 4: per-node combine + gamma + normalize -----------------
__launch_bounds__(256)
__global__ void k_apply(const float* __restrict__ spikes,
                        const float* __restrict__ theta,
                        const float* __restrict__ gamma,
                        const float* __restrict__ ws,
                        float* __restrict__ out) {
    int v = blockIdx.x*256 + threadIdx.x;        // node, < BATCH*NN
    int b = v / NN;
    int c = (v - b*NN) % CIN;
    int g = b*CIN + c;
    float scale = ws[SC_OFF + g*2], amin = ws[SC_OFF + g*2 + 1];
    float s = spikes[v];
    float a = s * scale;
    int bb = (int)((a - amin) * (4.0f * NB));
    bb = bb < 0 ? 0 : (bb > NB - 1 ? NB - 1 : bb);
    float sa, ca; sincosf(a, &sa, &ca);
    float4 th = ((const float4*)theta)[v];
    float4 gm = ((const float4*)gamma)[v];
    const float4* H4 = (const float4*)(ws + H_OFF + g * 8192);
    float thv[4] = {th.x, th.y, th.z, th.w};
    float cp4[4];
    #pragma unroll
    for (int d = 0; d < 4; ++d) {
        float sth, cth; sincosf(thv[d], &sth, &cth);
        float sf = fmaf(cth, sa,  sth*ca);
        float cf = fmaf(-sth, sa, cth*ca);
        float sp = fmaf(-cth, sa, sth*ca);
        float cq = fmaf(sth, sa,  cth*ca);
        float4 Plo = H4[(d*NB + bb)*2];
        float4 Phi = H4[(d*NB + bb)*2 + 1];
        float4 T   = H4[(d*NB + NB - 1)*2 + 1];
        float lowS = fmaf(0.25f - a, Plo.x, Plo.z);
        float lowC = fmaf(0.25f - a, Plo.y, Plo.w);
        float lower = cf*lowS - sf*lowC;
        float S4 = T.x - Phi.x, S5 = T.y - Phi.y;
        float S6 = T.z - Phi.z, S7 = T.w - Phi.w;
        float upS = fmaf(0.25f + a, S4, -S6);
        float upC = fmaf(0.25f + a, S5, -S7);
        float upper = cq*upS - sp*upC;
        cp4[d] = (lower + upper) * (1.0f / (float)NC);
    }
    float tx = gm.x + cp4[0], ty = gm.y + cp4[1];
    float tz = gm.z + cp4[2], tw = gm.w + cp4[3];
    float nrm = sqrtf(tx*tx + ty*ty + tz*tz + tw*tw);
    float inv = 1.0f / fmaxf(nrm, 1e-6f);
    ((float4*)out)[v] = make_float4(tx*inv, ty*inv, tz*inv, tw*inv);
}

extern "C" void kernel_launch(void* const* d_in, const int* in_sizes, int n_in,
                              void* d_out, int out_size, void* d_ws, size_t ws_size,
                              hipStream_t stream) {
    const float* theta  = (const float*)d_in[0];
    const float* gamma  = (const float*)d_in[1];
    const float* spikes = (const float*)d_in[2];
    float* out = (float*)d_out;
    float* ws  = (float*)d_ws;

    hipLaunchKernelGGL(k_stats, dim3(NG),      dim3(256), 0, stream, spikes, ws);
    hipLaunchKernelGGL(k_hist,  dim3(NG * 16), dim3(256), 0, stream, spikes, theta, ws);
    hipLaunchKernelGGL(k_scan,  dim3(NG * 4),  dim3(512), 0, stream, ws);
    hipLaunchKernelGGL(k_apply, dim3(BATCH*NN/256), dim3(256), 0, stream,
                       spikes, theta, gamma, ws, out);
}